// Round 9
// baseline (97.274 us; speedup 1.0000x reference)
//
#include <hip/hip_runtime.h>
#include <math.h>

#define CEPS 1e-8f

typedef __attribute__((ext_vector_type(8))) short bf16x8;
typedef __attribute__((ext_vector_type(4))) float f32x4;
typedef __attribute__((ext_vector_type(4))) unsigned int u32x4;
typedef __attribute__((ext_vector_type(2))) unsigned int u32x2;

__device__ __forceinline__ unsigned short f2bf(float f) {
    unsigned u = __builtin_bit_cast(unsigned, f);
    u += 0x7fffu + ((u >> 16) & 1u);            // round-nearest-even
    return (unsigned short)(u >> 16);
}

// ---- fused pack + towers, 32 rows/block, 512 threads, 2 blocks/CU ----
// Phase 0: each block packs 64 weight-fragment entries (hidden under gather),
// device-scope handshake, then towers. Waves 0-3 user, 4-7 item.
// Swapped-operand MFMA: D[wcol][erow] = mfma(Wfrag, efrag).

template<int F>
__device__ __forceinline__ void stage_emb(const int* __restrict__ ids,
                                          const float* __restrict__ table,
                                          unsigned short* e_s, int row0, int tid)
{
    constexpr int FC = F * 8;                    // 16B chunks per row
    constexpr int IT = (32 * FC) / 512;
    int idv[IT];
    #pragma unroll
    for (int it = 0; it < IT; ++it) {
        int c = tid + it * 512;
        int r = c / FC, f = (c % FC) >> 3;
        idv[it] = ids[(row0 + r) * F + f];
    }
    #pragma unroll
    for (int it = 0; it < IT; ++it) {
        int c = tid + it * 512;
        int r = c / FC, rem = c % FC;
        const float* src = table + (size_t)idv[it] * 64 + (rem & 7) * 8;
        float4 aa = *reinterpret_cast<const float4*>(src);
        float4 bb = *reinterpret_cast<const float4*>(src + 4);
        u32x4 pk;
        pk.x = f2bf(aa.x) | ((unsigned)f2bf(aa.y) << 16);
        pk.y = f2bf(aa.z) | ((unsigned)f2bf(aa.w) << 16);
        pk.z = f2bf(bb.x) | ((unsigned)f2bf(bb.y) << 16);
        pk.w = f2bf(bb.z) | ((unsigned)f2bf(bb.w) << 16);
        int byte = r * (F * 128) + rem * 16;
        byte ^= (r & 7) << 4;
        *reinterpret_cast<u32x4*>(reinterpret_cast<char*>(e_s) + byte) = pk;
    }
}

// LDS fragment read: 8 K-contiguous bf16 of row (ni*16+l15) at k-slice l4.
template<int KB>
__device__ __forceinline__ bf16x8 loadA(const unsigned short* s, int ks, int ni,
                                        int l15, int l4)
{
    int row = ni * 16 + l15;
    int byte = row * (KB * 2) + ks * 64 + l4 * 16;
    byte ^= (row & 7) << 4;
    return *reinterpret_cast<const bf16x8*>(
               reinterpret_cast<const char*>(s) + byte);
}

// GEMM1 (swapped): wave owns w-cols [wl*64, +64) (4 frags), 32 e-rows (2 frags).
template<int K1>
__device__ __forceinline__ void gemm1(
    const unsigned short* e_s, unsigned short* h_s,
    const unsigned short* __restrict__ W1p, const float* __restrict__ b1,
    int l15, int l4, int wl)
{
    constexpr int NKS = K1 / 32;
    f32x4 acc[4][2];
    #pragma unroll
    for (int mi = 0; mi < 4; ++mi)
        #pragma unroll
        for (int ni = 0; ni < 2; ++ni) acc[mi][ni] = (f32x4){0.f, 0.f, 0.f, 0.f};

    const unsigned short* Wbase = W1p + ((l4 * 256 + wl * 64 + l15) << 3);
    bf16x8 wf[3][4], ef[2][2];
    #pragma unroll
    for (int mi = 0; mi < 4; ++mi) {
        wf[0][mi] = *reinterpret_cast<const bf16x8*>(Wbase + (mi << 7));
        wf[1][mi] = *reinterpret_cast<const bf16x8*>(Wbase + 8192 + (mi << 7));
    }
    #pragma unroll
    for (int ni = 0; ni < 2; ++ni) ef[0][ni] = loadA<K1>(e_s, 0, ni, l15, l4);

    #pragma unroll
    for (int ks = 0; ks < NKS; ++ks) {
        if (ks + 2 < NKS) {
            #pragma unroll
            for (int mi = 0; mi < 4; ++mi)
                wf[(ks + 2) % 3][mi] = *reinterpret_cast<const bf16x8*>(
                    Wbase + (ks + 2) * 8192 + (mi << 7));
        }
        if (ks + 1 < NKS) {
            #pragma unroll
            for (int ni = 0; ni < 2; ++ni)
                ef[(ks + 1) & 1][ni] = loadA<K1>(e_s, ks + 1, ni, l15, l4);
        }
        __builtin_amdgcn_s_setprio(1);
        #pragma unroll
        for (int mi = 0; mi < 4; ++mi)
            #pragma unroll
            for (int ni = 0; ni < 2; ++ni)
                acc[mi][ni] = __builtin_amdgcn_mfma_f32_16x16x32_bf16(
                                  wf[ks % 3][mi], ef[ks & 1][ni], acc[mi][ni], 0, 0, 0);
        __builtin_amdgcn_s_setprio(0);
    }
    // epilogue: bias + relu; lane holds 4 consecutive w-cols of one row -> b64
    #pragma unroll
    for (int mi = 0; mi < 4; ++mi) {
        const float4 bb = *reinterpret_cast<const float4*>(
                              &b1[wl * 64 + mi * 16 + l4 * 4]);
        #pragma unroll
        for (int ni = 0; ni < 2; ++ni) {
            float v0 = acc[mi][ni][0] + bb.x; v0 = v0 > 0.f ? v0 : 0.f;
            float v1 = acc[mi][ni][1] + bb.y; v1 = v1 > 0.f ? v1 : 0.f;
            float v2 = acc[mi][ni][2] + bb.z; v2 = v2 > 0.f ? v2 : 0.f;
            float v3 = acc[mi][ni][3] + bb.w; v3 = v3 > 0.f ? v3 : 0.f;
            u32x2 d;
            d.x = f2bf(v0) | ((unsigned)f2bf(v1) << 16);
            d.y = f2bf(v2) | ((unsigned)f2bf(v3) << 16);
            int row = ni * 16 + l15;
            int w0c = wl * 64 + mi * 16 + l4 * 4;
            int byte = (row * 256 + w0c) * 2;
            byte ^= (row & 7) << 4;
            *reinterpret_cast<u32x2*>(reinterpret_cast<char*>(h_s) + byte) = d;
        }
    }
}

// GEMM2 (swapped): wave owns out-cols [wl*32, +32) (2 frags), 32 rows (2 frags).
__device__ __forceinline__ void gemm2(
    const unsigned short* h_s, const unsigned short* __restrict__ W2p,
    f32x4 (&acc)[2][2], int l15, int l4, int wl)
{
    #pragma unroll
    for (int mi = 0; mi < 2; ++mi)
        #pragma unroll
        for (int ni = 0; ni < 2; ++ni) acc[mi][ni] = (f32x4){0.f, 0.f, 0.f, 0.f};

    const unsigned short* Wbase = W2p + ((l4 * 128 + wl * 32 + l15) << 3);
    bf16x8 wf[3][2], hf[2][2];
    #pragma unroll
    for (int mi = 0; mi < 2; ++mi) {
        wf[0][mi] = *reinterpret_cast<const bf16x8*>(Wbase + (mi << 7));
        wf[1][mi] = *reinterpret_cast<const bf16x8*>(Wbase + 4096 + (mi << 7));
    }
    #pragma unroll
    for (int ni = 0; ni < 2; ++ni) hf[0][ni] = loadA<256>(h_s, 0, ni, l15, l4);

    #pragma unroll
    for (int ks = 0; ks < 8; ++ks) {
        if (ks + 2 < 8) {
            #pragma unroll
            for (int mi = 0; mi < 2; ++mi)
                wf[(ks + 2) % 3][mi] = *reinterpret_cast<const bf16x8*>(
                    Wbase + (ks + 2) * 4096 + (mi << 7));
        }
        if (ks + 1 < 8) {
            #pragma unroll
            for (int ni = 0; ni < 2; ++ni)
                hf[(ks + 1) & 1][ni] = loadA<256>(h_s, ks + 1, ni, l15, l4);
        }
        __builtin_amdgcn_s_setprio(1);
        #pragma unroll
        for (int mi = 0; mi < 2; ++mi)
            #pragma unroll
            for (int ni = 0; ni < 2; ++ni)
                acc[mi][ni] = __builtin_amdgcn_mfma_f32_16x16x32_bf16(
                                  wf[ks % 3][mi], hf[ks & 1][ni], acc[mi][ni], 0, 0, 0);
        __builtin_amdgcn_s_setprio(0);
    }
}

__global__ __launch_bounds__(512, 4)
void fused_sbc(const int* __restrict__ user_ids,  const int* __restrict__ item_ids,
               const float* __restrict__ user_table, const float* __restrict__ item_table,
               const float* __restrict__ uW1, const float* __restrict__ ub1,
               const float* __restrict__ uW2, const float* __restrict__ ub2,
               const float* __restrict__ iW1, const float* __restrict__ ib1,
               const float* __restrict__ iW2, const float* __restrict__ ib2,
               const float* __restrict__ sw,
               unsigned short* __restrict__ wp, int* __restrict__ counter,
               float* __restrict__ out, int B, int nn1)
{
    unsigned short* uW1p = wp;               // [512/8][256][8]
    unsigned short* uW2p = wp + 131072;
    unsigned short* iW1p = wp + 163840;
    unsigned short* iW2p = wp + 229376;

    __shared__ __align__(16) unsigned short smem[40960];   // 80 KB -> 2 blk/CU
    unsigned short* e_u = smem;                  // [32][512]  32 KB
    unsigned short* e_i = smem + 16384;          // [32][256]  16 KB
    unsigned short* h_u = smem + 24576;          // [32][256]  16 KB
    unsigned short* h_i = smem + 32768;          // [32][256]  16 KB
    float* V_lds = reinterpret_cast<float*>(smem);          // [32][132] over e_u
    float* red   = reinterpret_cast<float*>(smem + 16384);  // [4][32][3] over e_i

    const int tid  = threadIdx.x;
    const int lane = tid & 63;
    const int w    = tid >> 6;
    const int l15  = lane & 15, l4 = lane >> 4;
    const int role = w >> 2;                     // 0 = user, 1 = item
    const int wl   = w & 3;
    const int row0 = blockIdx.x * 32;

    // ---- phase 0: distributed weight pack (64 entries/block) ----
    if (tid < 64) {
        for (int g = blockIdx.x * 64 + tid; g < 32768; g += gridDim.x * 64) {
            const float* src; unsigned short* dst; int N; int base;
            if (g < 16384)      { src = uW1; dst = uW1p; N = 256; base = 0;     }
            else if (g < 20480) { src = uW2; dst = uW2p; N = 128; base = 16384; }
            else if (g < 28672) { src = iW1; dst = iW1p; N = 256; base = 20480; }
            else                { src = iW2; dst = iW2p; N = 128; base = 28672; }
            int i = g - base;
            int kg = i / N, n = i - kg * N;
            unsigned short tmp[8];
            #pragma unroll
            for (int j = 0; j < 8; ++j)
                tmp[j] = f2bf(src[(kg * 8 + j) * N + n]);
            *reinterpret_cast<bf16x8*>(dst + ((size_t)i << 3)) =
                *reinterpret_cast<bf16x8*>(tmp);
        }
        __threadfence();
    }

    // ---- stage both towers' embeddings (no weights needed) ----
    stage_emb<8>(user_ids, user_table, e_u, row0, tid);
    stage_emb<4>(item_ids, item_table, e_i, row0, tid);
    __syncthreads();                             // B1: staged + pack stores done

    // ---- handshake: wait for all blocks' pack contributions ----
    if (tid == 0) {
        __hip_atomic_fetch_add(counter, 1, __ATOMIC_ACQ_REL,
                               __HIP_MEMORY_SCOPE_AGENT);
        while (__hip_atomic_load(counter, __ATOMIC_ACQUIRE,
                                 __HIP_MEMORY_SCOPE_AGENT) < (int)gridDim.x) {
            __builtin_amdgcn_s_sleep(2);
        }
    }
    __syncthreads();                             // B1b: all weights packed

    if (role == 0) gemm1<512>(e_u, h_u, uW1p, ub1, l15, l4, wl);
    else           gemm1<256>(e_i, h_i, iW1p, ib1, l15, l4, wl);
    __syncthreads();                             // B2: h_u, h_i ready

    f32x4 acc2[2][2];
    if (role == 0) gemm2(h_u, uW2p, acc2, l15, l4, wl);
    else           gemm2(h_i, iW2p, acc2, l15, l4, wl);

    // item waves: relu(V) -> V_lds + ||v||^2 partials
    if (role == 1) {
        float pv[2] = {0.f, 0.f};
        #pragma unroll
        for (int mi = 0; mi < 2; ++mi) {
            const int colb = wl * 32 + mi * 16 + l4 * 4;
            const float4 bv = *reinterpret_cast<const float4*>(&ib2[colb]);
            #pragma unroll
            for (int ni = 0; ni < 2; ++ni) {
                int row = ni * 16 + l15;
                float v0 = acc2[mi][ni][0] + bv.x; v0 = v0 > 0.f ? v0 : 0.f;
                float v1 = acc2[mi][ni][1] + bv.y; v1 = v1 > 0.f ? v1 : 0.f;
                float v2 = acc2[mi][ni][2] + bv.z; v2 = v2 > 0.f ? v2 : 0.f;
                float v3 = acc2[mi][ni][3] + bv.w; v3 = v3 > 0.f ? v3 : 0.f;
                float4 vv = {v0, v1, v2, v3};
                *reinterpret_cast<float4*>(&V_lds[row * 132 + colb]) = vv;
                pv[ni] += v0 * v0 + v1 * v1 + v2 * v2 + v3 * v3;
            }
        }
        #pragma unroll
        for (int ni = 0; ni < 2; ++ni) {
            pv[ni] += __shfl_xor(pv[ni], 16);
            pv[ni] += __shfl_xor(pv[ni], 32);
        }
        if (l4 == 0) {
            #pragma unroll
            for (int ni = 0; ni < 2; ++ni)
                red[(wl * 32 + ni * 16 + l15) * 3 + 2] = pv[ni];
        }
    }
    __syncthreads();                             // B3: V published

    // user waves: relu(U), dot + ||u||^2 partials
    if (role == 0) {
        float pd[2] = {0.f, 0.f}, pu[2] = {0.f, 0.f};
        #pragma unroll
        for (int mi = 0; mi < 2; ++mi) {
            const int colb = wl * 32 + mi * 16 + l4 * 4;
            const float4 bu = *reinterpret_cast<const float4*>(&ub2[colb]);
            #pragma unroll
            for (int ni = 0; ni < 2; ++ni) {
                int row = ni * 16 + l15;
                float u0 = acc2[mi][ni][0] + bu.x; u0 = u0 > 0.f ? u0 : 0.f;
                float u1 = acc2[mi][ni][1] + bu.y; u1 = u1 > 0.f ? u1 : 0.f;
                float u2 = acc2[mi][ni][2] + bu.z; u2 = u2 > 0.f ? u2 : 0.f;
                float u3 = acc2[mi][ni][3] + bu.w; u3 = u3 > 0.f ? u3 : 0.f;
                const float4 vv = *reinterpret_cast<const float4*>(
                                      &V_lds[row * 132 + colb]);
                pd[ni] += u0 * vv.x + u1 * vv.y + u2 * vv.z + u3 * vv.w;
                pu[ni] += u0 * u0 + u1 * u1 + u2 * u2 + u3 * u3;
            }
        }
        #pragma unroll
        for (int ni = 0; ni < 2; ++ni) {
            pd[ni] += __shfl_xor(pd[ni], 16);
            pd[ni] += __shfl_xor(pd[ni], 32);
            pu[ni] += __shfl_xor(pu[ni], 16);
            pu[ni] += __shfl_xor(pu[ni], 32);
        }
        if (l4 == 0) {
            #pragma unroll
            for (int ni = 0; ni < 2; ++ni) {
                red[(wl * 32 + ni * 16 + l15) * 3 + 0] = pd[ni];
                red[(wl * 32 + ni * 16 + l15) * 3 + 1] = pu[ni];
            }
        }
    }
    __syncthreads();                             // B4: partials in red

    // final reduce + y + scatter
    if (tid < 32) {
        int row = tid;
        float d = 0.f, su = 0.f, sv = 0.f;
        #pragma unroll
        for (int cg = 0; cg < 4; ++cg) {
            d  += red[(cg * 32 + row) * 3 + 0];
            su += red[(cg * 32 + row) * 3 + 1];
            sv += red[(cg * 32 + row) * 3 + 2];
        }
        float un = fmaxf(sqrtf(su), CEPS);
        float vn = fmaxf(sqrtf(sv), CEPS);
        int grow = row0 + row;
        float yv = d / (un * vn) - logf(sw[grow]);
        for (int j = 0; j < nn1; ++j) {
            int idx = grow - j;
            if (idx < 0) idx += B;
            out[idx * nn1 + j] = yv;
        }
    }
}

extern "C" void kernel_launch(void* const* d_in, const int* in_sizes, int n_in,
                              void* d_out, int out_size, void* d_ws, size_t ws_size,
                              hipStream_t stream)
{
    const int*   user_ids   = (const int*)  d_in[0];
    const int*   item_ids   = (const int*)  d_in[1];
    const float* sw         = (const float*)d_in[2];
    const float* user_table = (const float*)d_in[3];
    const float* item_table = (const float*)d_in[4];
    const float* uW1        = (const float*)d_in[5];
    const float* ub1        = (const float*)d_in[6];
    const float* uW2        = (const float*)d_in[7];
    const float* ub2        = (const float*)d_in[8];
    const float* iW1        = (const float*)d_in[9];
    const float* ib1        = (const float*)d_in[10];
    const float* iW2        = (const float*)d_in[11];
    const float* ib2        = (const float*)d_in[12];

    const int B   = in_sizes[2];       // 16384
    const int nn1 = out_size / B;      // n_neg + 1

    unsigned short* wp = (unsigned short*)d_ws;      // 512 KB packed weights
    int* counter = (int*)(wp + 262144);
    float* out = (float*)d_out;

    hipMemsetAsync(counter, 0, sizeof(int), stream);
    fused_sbc<<<B / 32, 512, 0, stream>>>(user_ids, item_ids,
                                          user_table, item_table,
                                          uW1, ub1, uW2, ub2,
                                          iW1, ib1, iW2, ib2,
                                          sw, wp, counter, out, B, nn1);
}

// Round 10
// 36.970 us; speedup vs baseline: 2.6311x; 2.6311x over previous
//
#include <hip/hip_runtime.h>
#include <math.h>

#define CEPS 1e-8f

typedef __attribute__((ext_vector_type(8))) short bf16x8;
typedef __attribute__((ext_vector_type(4))) float f32x4;
typedef __attribute__((ext_vector_type(4))) unsigned int u32x4;
typedef __attribute__((ext_vector_type(2))) unsigned int u32x2;

__device__ __forceinline__ unsigned short f2bf(float f) {
    unsigned u = __builtin_bit_cast(unsigned, f);
    u += 0x7fffu + ((u >> 16) & 1u);            // round-nearest-even
    return (unsigned short)(u >> 16);
}

// Pack weights fp32 -> bf16, MFMA fragment layout [K/8][N][8].
__global__ __launch_bounds__(256)
void pack_all(const float* __restrict__ uW1, const float* __restrict__ uW2,
              const float* __restrict__ iW1, const float* __restrict__ iW2,
              unsigned short* __restrict__ o1, unsigned short* __restrict__ o2,
              unsigned short* __restrict__ o3, unsigned short* __restrict__ o4)
{
    int g = blockIdx.x * 256 + threadIdx.x;     // 32768 entries
    const float* src; unsigned short* dst; int N; int base;
    if (g < 16384)      { src = uW1; dst = o1; N = 256; base = 0;     }
    else if (g < 20480) { src = uW2; dst = o2; N = 128; base = 16384; }
    else if (g < 28672) { src = iW1; dst = o3; N = 256; base = 20480; }
    else                { src = iW2; dst = o4; N = 128; base = 28672; }
    int i = g - base;
    int kg = i / N, n = i - kg * N;
    unsigned short tmp[8];
    #pragma unroll
    for (int j = 0; j < 8; ++j)
        tmp[j] = f2bf(src[(kg * 8 + j) * N + n]);
    *reinterpret_cast<bf16x8*>(dst + ((size_t)i << 3)) =
        *reinterpret_cast<bf16x8*>(tmp);
}

// ---- fused towers: 16 rows/block, 512 threads (8 waves), grid B/16 ----
// Sequential towers; LDS ~25.5 KB -> 4 blocks/CU resident (up to 32 waves/CU).
// Swapped-operand MFMA: D[wcol][erow] = mfma(Wfrag, efrag).
// LDS regions: e_u[16][512] (16KB) | hbuf[16][256] (8KB) | red[8][16][3].
// hbuf holds user-h, then item-e; item-h overlays retired e_u.

// LDS fragment read: 8 K-contiguous bf16 of row l15 at k-slice (ks,l4).
template<int KB>
__device__ __forceinline__ bf16x8 loadA(const unsigned short* s, int ks,
                                        int l15, int l4)
{
    int byte = l15 * (KB * 2) + ks * 64 + l4 * 16;
    byte ^= (l15 & 7) << 4;
    return *reinterpret_cast<const bf16x8*>(
               reinterpret_cast<const char*>(s) + byte);
}

// GEMM1: h[16][256] = relu(e[16][K1] @ W1 + b1). Wave: 32 cols (2 mi frags).
template<int K1>
__device__ __forceinline__ void gemm1(
    const unsigned short* e_s, unsigned short* h_s,
    const unsigned short* __restrict__ W1p, const float* __restrict__ b1,
    int l15, int l4, int wl)
{
    constexpr int NKS = K1 / 32;
    f32x4 acc[2];
    acc[0] = (f32x4){0.f, 0.f, 0.f, 0.f};
    acc[1] = (f32x4){0.f, 0.f, 0.f, 0.f};

    const unsigned short* Wbase = W1p + ((l4 * 256 + wl * 32 + l15) << 3);
    bf16x8 wf[3][2], ef[2];
    #pragma unroll
    for (int mi = 0; mi < 2; ++mi) {
        wf[0][mi] = *reinterpret_cast<const bf16x8*>(Wbase + (mi << 7));
        wf[1][mi] = *reinterpret_cast<const bf16x8*>(Wbase + 8192 + (mi << 7));
    }
    ef[0] = loadA<K1>(e_s, 0, l15, l4);

    #pragma unroll
    for (int ks = 0; ks < NKS; ++ks) {
        if (ks + 2 < NKS) {
            #pragma unroll
            for (int mi = 0; mi < 2; ++mi)
                wf[(ks + 2) % 3][mi] = *reinterpret_cast<const bf16x8*>(
                    Wbase + (ks + 2) * 8192 + (mi << 7));
        }
        if (ks + 1 < NKS)
            ef[(ks + 1) & 1] = loadA<K1>(e_s, ks + 1, l15, l4);
        __builtin_amdgcn_s_setprio(1);
        #pragma unroll
        for (int mi = 0; mi < 2; ++mi)
            acc[mi] = __builtin_amdgcn_mfma_f32_16x16x32_bf16(
                          wf[ks % 3][mi], ef[ks & 1], acc[mi], 0, 0, 0);
        __builtin_amdgcn_s_setprio(0);
    }
    // epilogue: bias + relu; lane holds 4 consecutive w-cols of row l15
    #pragma unroll
    for (int mi = 0; mi < 2; ++mi) {
        const int colb = wl * 32 + mi * 16 + l4 * 4;
        const float4 bb = *reinterpret_cast<const float4*>(&b1[colb]);
        float v0 = acc[mi][0] + bb.x; v0 = v0 > 0.f ? v0 : 0.f;
        float v1 = acc[mi][1] + bb.y; v1 = v1 > 0.f ? v1 : 0.f;
        float v2 = acc[mi][2] + bb.z; v2 = v2 > 0.f ? v2 : 0.f;
        float v3 = acc[mi][3] + bb.w; v3 = v3 > 0.f ? v3 : 0.f;
        u32x2 d;
        d.x = f2bf(v0) | ((unsigned)f2bf(v1) << 16);
        d.y = f2bf(v2) | ((unsigned)f2bf(v3) << 16);
        int byte = (l15 * 256 + colb) * 2;
        byte ^= (l15 & 7) << 4;
        *reinterpret_cast<u32x2*>(reinterpret_cast<char*>(h_s) + byte) = d;
    }
}

// GEMM2: acc = h[16][256] @ W2 (cols wl*16 + l4*4 .. +3 per lane).
__device__ __forceinline__ f32x4 gemm2(
    const unsigned short* h_s, const unsigned short* __restrict__ W2p,
    int l15, int l4, int wl)
{
    f32x4 acc = (f32x4){0.f, 0.f, 0.f, 0.f};
    const unsigned short* Wbase = W2p + ((l4 * 128 + wl * 16 + l15) << 3);
    bf16x8 wf[3], hf[2];
    wf[0] = *reinterpret_cast<const bf16x8*>(Wbase);
    wf[1] = *reinterpret_cast<const bf16x8*>(Wbase + 4096);
    hf[0] = loadA<256>(h_s, 0, l15, l4);

    #pragma unroll
    for (int ks = 0; ks < 8; ++ks) {
        if (ks + 2 < 8)
            wf[(ks + 2) % 3] = *reinterpret_cast<const bf16x8*>(
                                   Wbase + (ks + 2) * 4096);
        if (ks + 1 < 8)
            hf[(ks + 1) & 1] = loadA<256>(h_s, ks + 1, l15, l4);
        __builtin_amdgcn_s_setprio(1);
        acc = __builtin_amdgcn_mfma_f32_16x16x32_bf16(
                  wf[ks % 3], hf[ks & 1], acc, 0, 0, 0);
        __builtin_amdgcn_s_setprio(0);
    }
    return acc;
}

__global__ __launch_bounds__(512, 6)
void fused_sbc(const int* __restrict__ user_ids,  const int* __restrict__ item_ids,
               const float* __restrict__ user_table, const float* __restrict__ item_table,
               const unsigned short* __restrict__ uW1p, const float* __restrict__ ub1,
               const unsigned short* __restrict__ uW2p, const float* __restrict__ ub2,
               const unsigned short* __restrict__ iW1p, const float* __restrict__ ib1,
               const unsigned short* __restrict__ iW2p, const float* __restrict__ ib2,
               const float* __restrict__ sw, float* __restrict__ out,
               int B, int nn1)
{
    __shared__ __align__(16) unsigned short smem[13056];   // 25.5 KB
    unsigned short* e_u  = smem;                 // [16][512] 16 KB (later: h_i)
    unsigned short* hbuf = smem + 8192;          // [16][256]  8 KB (h_u, then e_i)
    float* red = reinterpret_cast<float*>(smem + 12288);   // [8][16][3]

    const int tid  = threadIdx.x;
    const int lane = tid & 63;
    const int wl   = tid >> 6;                   // wave 0..7
    const int l15  = lane & 15, l4 = lane >> 4;
    const int row0 = blockIdx.x * 16;

    // ---- item embeddings: reg-stage now (T14), write to LDS much later ----
    const int r_i = tid >> 5, rem_i = tid & 31;  // 512 chunks = 16 rows x 32
    u32x4 ipk;
    {
        int f_i = rem_i >> 3, ci = rem_i & 7;
        int id = item_ids[(row0 + r_i) * 4 + f_i];
        const float* src = item_table + (size_t)id * 64 + ci * 8;
        float4 aa = *reinterpret_cast<const float4*>(src);
        float4 bb = *reinterpret_cast<const float4*>(src + 4);
        ipk.x = f2bf(aa.x) | ((unsigned)f2bf(aa.y) << 16);
        ipk.y = f2bf(aa.z) | ((unsigned)f2bf(aa.w) << 16);
        ipk.z = f2bf(bb.x) | ((unsigned)f2bf(bb.y) << 16);
        ipk.w = f2bf(bb.z) | ((unsigned)f2bf(bb.w) << 16);
    }

    // ---- stage user embeddings -> e_u (2 chunks/thread) ----
    {
        int idv[2];
        #pragma unroll
        for (int it = 0; it < 2; ++it) {
            int c = tid + it * 512;
            int r = c >> 6, f = (c & 63) >> 3;
            idv[it] = user_ids[(row0 + r) * 8 + f];
        }
        #pragma unroll
        for (int it = 0; it < 2; ++it) {
            int c = tid + it * 512;
            int r = c >> 6, rem = c & 63, ci = rem & 7;
            const float* src = user_table + (size_t)idv[it] * 64 + ci * 8;
            float4 aa = *reinterpret_cast<const float4*>(src);
            float4 bb = *reinterpret_cast<const float4*>(src + 4);
            u32x4 pk;
            pk.x = f2bf(aa.x) | ((unsigned)f2bf(aa.y) << 16);
            pk.y = f2bf(aa.z) | ((unsigned)f2bf(aa.w) << 16);
            pk.z = f2bf(bb.x) | ((unsigned)f2bf(bb.y) << 16);
            pk.w = f2bf(bb.z) | ((unsigned)f2bf(bb.w) << 16);
            int byte = r * 1024 + rem * 16;
            byte ^= (r & 7) << 4;
            *reinterpret_cast<u32x4*>(reinterpret_cast<char*>(e_u) + byte) = pk;
        }
    }
    __syncthreads();                             // B1: e_u staged

    // ---- user tower ----
    gemm1<512>(e_u, hbuf, uW1p, ub1, l15, l4, wl);
    __syncthreads();                             // B2: h_u complete
    f32x4 au = gemm2(hbuf, uW2p, l15, l4, wl);
    float u0, u1, u2, u3;
    {
        const float4 bu = *reinterpret_cast<const float4*>(
                              &ub2[wl * 16 + l4 * 4]);
        u0 = au[0] + bu.x; u0 = u0 > 0.f ? u0 : 0.f;
        u1 = au[1] + bu.y; u1 = u1 > 0.f ? u1 : 0.f;
        u2 = au[2] + bu.z; u2 = u2 > 0.f ? u2 : 0.f;
        u3 = au[3] + bu.w; u3 = u3 > 0.f ? u3 : 0.f;
    }
    __syncthreads();                             // B3: h_u reads done

    // ---- item embeddings -> hbuf (retired h_u region) ----
    {
        int byte = r_i * 512 + rem_i * 16;
        byte ^= (r_i & 7) << 4;
        *reinterpret_cast<u32x4*>(reinterpret_cast<char*>(hbuf) + byte) = ipk;
    }
    __syncthreads();                             // B4: e_i staged

    // ---- item tower (h_i goes into retired e_u region) ----
    gemm1<256>(hbuf, e_u, iW1p, ib1, l15, l4, wl);
    __syncthreads();                             // B5: h_i complete
    f32x4 av = gemm2(e_u, iW2p, l15, l4, wl);
    float v0, v1, v2, v3;
    {
        const float4 bv = *reinterpret_cast<const float4*>(
                              &ib2[wl * 16 + l4 * 4]);
        v0 = av[0] + bv.x; v0 = v0 > 0.f ? v0 : 0.f;
        v1 = av[1] + bv.y; v1 = v1 > 0.f ? v1 : 0.f;
        v2 = av[2] + bv.z; v2 = v2 > 0.f ? v2 : 0.f;
        v3 = av[3] + bv.w; v3 = v3 > 0.f ? v3 : 0.f;
    }

    // ---- cosine partials: same lane holds U and V at same (row,col) ----
    float pd = u0 * v0 + u1 * v1 + u2 * v2 + u3 * v3;
    float pu = u0 * u0 + u1 * u1 + u2 * u2 + u3 * u3;
    float pv = v0 * v0 + v1 * v1 + v2 * v2 + v3 * v3;
    pd += __shfl_xor(pd, 16); pd += __shfl_xor(pd, 32);
    pu += __shfl_xor(pu, 16); pu += __shfl_xor(pu, 32);
    pv += __shfl_xor(pv, 16); pv += __shfl_xor(pv, 32);
    if (l4 == 0) {
        red[(wl * 16 + l15) * 3 + 0] = pd;
        red[(wl * 16 + l15) * 3 + 1] = pu;
        red[(wl * 16 + l15) * 3 + 2] = pv;
    }
    __syncthreads();                             // B6: partials in red

    if (tid < 16) {
        int row = tid;
        float d = 0.f, su = 0.f, sv = 0.f;
        #pragma unroll
        for (int cg = 0; cg < 8; ++cg) {
            d  += red[(cg * 16 + row) * 3 + 0];
            su += red[(cg * 16 + row) * 3 + 1];
            sv += red[(cg * 16 + row) * 3 + 2];
        }
        float un = fmaxf(sqrtf(su), CEPS);
        float vn = fmaxf(sqrtf(sv), CEPS);
        int grow = row0 + row;
        float yv = d / (un * vn) - logf(sw[grow]);
        for (int j = 0; j < nn1; ++j) {
            int idx = grow - j;
            if (idx < 0) idx += B;
            out[idx * nn1 + j] = yv;
        }
    }
}

extern "C" void kernel_launch(void* const* d_in, const int* in_sizes, int n_in,
                              void* d_out, int out_size, void* d_ws, size_t ws_size,
                              hipStream_t stream)
{
    const int*   user_ids   = (const int*)  d_in[0];
    const int*   item_ids   = (const int*)  d_in[1];
    const float* sw         = (const float*)d_in[2];
    const float* user_table = (const float*)d_in[3];
    const float* item_table = (const float*)d_in[4];
    const float* uW1        = (const float*)d_in[5];
    const float* ub1        = (const float*)d_in[6];
    const float* uW2        = (const float*)d_in[7];
    const float* ub2        = (const float*)d_in[8];
    const float* iW1        = (const float*)d_in[9];
    const float* ib1        = (const float*)d_in[10];
    const float* iW2        = (const float*)d_in[11];
    const float* ib2        = (const float*)d_in[12];

    const int B   = in_sizes[2];       // 16384
    const int nn1 = out_size / B;      // n_neg + 1

    unsigned short* wp   = (unsigned short*)d_ws;
    unsigned short* uW1p = wp;               // 131072
    unsigned short* uW2p = wp + 131072;      // 32768
    unsigned short* iW1p = wp + 163840;      // 65536
    unsigned short* iW2p = wp + 229376;      // 32768
    float* out = (float*)d_out;

    pack_all<<<128, 256, 0, stream>>>(uW1, uW2, iW1, iW2,
                                      uW1p, uW2p, iW1p, iW2p);
    fused_sbc<<<B / 16, 512, 0, stream>>>(user_ids, item_ids,
                                          user_table, item_table,
                                          uW1p, ub1, uW2p, ub2,
                                          iW1p, ib1, iW2p, ib2,
                                          sw, out, B, nn1);
}

// Round 11
// 28.419 us; speedup vs baseline: 3.4228x; 1.3009x over previous
//
#include <hip/hip_runtime.h>
#include <math.h>

#define CEPS 1e-8f

typedef __attribute__((ext_vector_type(8))) short bf16x8;
typedef __attribute__((ext_vector_type(4))) float f32x4;
typedef __attribute__((ext_vector_type(4))) unsigned int u32x4;
typedef __attribute__((ext_vector_type(2))) unsigned int u32x2;

__device__ __forceinline__ unsigned short f2bf(float f) {
    unsigned u = __builtin_bit_cast(unsigned, f);
    u += 0x7fffu + ((u >> 16) & 1u);            // round-nearest-even
    return (unsigned short)(u >> 16);
}

// Pack weights fp32 -> bf16, MFMA fragment layout [K/8][N][8].
__global__ __launch_bounds__(256)
void pack_all(const float* __restrict__ uW1, const float* __restrict__ uW2,
              const float* __restrict__ iW1, const float* __restrict__ iW2,
              unsigned short* __restrict__ o1, unsigned short* __restrict__ o2,
              unsigned short* __restrict__ o3, unsigned short* __restrict__ o4)
{
    int g = blockIdx.x * 256 + threadIdx.x;     // 32768 entries
    const float* src; unsigned short* dst; int N; int base;
    if (g < 16384)      { src = uW1; dst = o1; N = 256; base = 0;     }
    else if (g < 20480) { src = uW2; dst = o2; N = 128; base = 16384; }
    else if (g < 28672) { src = iW1; dst = o3; N = 256; base = 20480; }
    else                { src = iW2; dst = o4; N = 128; base = 28672; }
    int i = g - base;
    int kg = i / N, n = i - kg * N;
    unsigned short tmp[8];
    #pragma unroll
    for (int j = 0; j < 8; ++j)
        tmp[j] = f2bf(src[(kg * 8 + j) * N + n]);
    *reinterpret_cast<bf16x8*>(dst + ((size_t)i << 3)) =
        *reinterpret_cast<bf16x8*>(tmp);
}

// ---- fused towers, 32 rows/block, 512 threads (8 waves), 2 blocks/CU ----
// Waves 0-3: user tower.  Waves 4-7: item tower (concurrent).
// Swapped-operand MFMA: D[wcol][erow] = mfma(Wfrag, efrag).
// Both weight-rotation slots preloaded BEFORE staging -> L2 warm-up hidden
// under the HBM gather phase.

template<int F>
__device__ __forceinline__ void stage_emb(const int* __restrict__ ids,
                                          const float* __restrict__ table,
                                          unsigned short* e_s, int row0, int tid)
{
    constexpr int FC = F * 8;                    // 16B chunks per row
    constexpr int IT = (32 * FC) / 512;
    int idv[IT];
    #pragma unroll
    for (int it = 0; it < IT; ++it) {
        int c = tid + it * 512;
        int r = c / FC, f = (c % FC) >> 3;
        idv[it] = ids[(row0 + r) * F + f];
    }
    #pragma unroll
    for (int it = 0; it < IT; ++it) {
        int c = tid + it * 512;
        int r = c / FC, rem = c % FC;
        const float* src = table + (size_t)idv[it] * 64 + (rem & 7) * 8;
        float4 aa = *reinterpret_cast<const float4*>(src);
        float4 bb = *reinterpret_cast<const float4*>(src + 4);
        u32x4 pk;
        pk.x = f2bf(aa.x) | ((unsigned)f2bf(aa.y) << 16);
        pk.y = f2bf(aa.z) | ((unsigned)f2bf(aa.w) << 16);
        pk.z = f2bf(bb.x) | ((unsigned)f2bf(bb.y) << 16);
        pk.w = f2bf(bb.z) | ((unsigned)f2bf(bb.w) << 16);
        int byte = r * (F * 128) + rem * 16;
        byte ^= (r & 7) << 4;
        *reinterpret_cast<u32x4*>(reinterpret_cast<char*>(e_s) + byte) = pk;
    }
}

// LDS fragment read: 8 K-contiguous bf16 of row (ni*16+l15) at k-slice l4.
template<int KB>
__device__ __forceinline__ bf16x8 loadA(const unsigned short* s, int ks, int ni,
                                        int l15, int l4)
{
    int row = ni * 16 + l15;
    int byte = row * (KB * 2) + ks * 64 + l4 * 16;
    byte ^= (row & 7) << 4;
    return *reinterpret_cast<const bf16x8*>(
               reinterpret_cast<const char*>(s) + byte);
}

// GEMM1 (swapped): wave owns w-cols [wl*64, +64) (4 frags), 32 e-rows (2 frags).
template<int K1>
__device__ __forceinline__ void gemm1(
    const unsigned short* e_s, unsigned short* h_s,
    const unsigned short* __restrict__ W1p, const float* __restrict__ b1,
    int l15, int l4, int wl, const bf16x8 (&w01)[2][4])
{
    constexpr int NKS = K1 / 32;
    f32x4 acc[4][2];
    #pragma unroll
    for (int mi = 0; mi < 4; ++mi)
        #pragma unroll
        for (int ni = 0; ni < 2; ++ni) acc[mi][ni] = (f32x4){0.f, 0.f, 0.f, 0.f};

    const unsigned short* Wbase = W1p + ((l4 * 256 + wl * 64 + l15) << 3);
    bf16x8 wf[3][4], ef[2][2];
    #pragma unroll
    for (int mi = 0; mi < 4; ++mi) {
        wf[0][mi] = w01[0][mi];
        wf[1][mi] = w01[1][mi];
    }
    #pragma unroll
    for (int ni = 0; ni < 2; ++ni) ef[0][ni] = loadA<K1>(e_s, 0, ni, l15, l4);

    #pragma unroll
    for (int ks = 0; ks < NKS; ++ks) {
        if (ks + 2 < NKS) {
            #pragma unroll
            for (int mi = 0; mi < 4; ++mi)
                wf[(ks + 2) % 3][mi] = *reinterpret_cast<const bf16x8*>(
                    Wbase + (ks + 2) * 8192 + (mi << 7));
        }
        if (ks + 1 < NKS) {
            #pragma unroll
            for (int ni = 0; ni < 2; ++ni)
                ef[(ks + 1) & 1][ni] = loadA<K1>(e_s, ks + 1, ni, l15, l4);
        }
        __builtin_amdgcn_s_setprio(1);
        #pragma unroll
        for (int mi = 0; mi < 4; ++mi)
            #pragma unroll
            for (int ni = 0; ni < 2; ++ni)
                acc[mi][ni] = __builtin_amdgcn_mfma_f32_16x16x32_bf16(
                                  wf[ks % 3][mi], ef[ks & 1][ni], acc[mi][ni], 0, 0, 0);
        __builtin_amdgcn_s_setprio(0);
    }
    // epilogue: bias + relu; lane holds 4 consecutive w-cols of one row -> b64
    #pragma unroll
    for (int mi = 0; mi < 4; ++mi) {
        const float4 bb = *reinterpret_cast<const float4*>(
                              &b1[wl * 64 + mi * 16 + l4 * 4]);
        #pragma unroll
        for (int ni = 0; ni < 2; ++ni) {
            float v0 = acc[mi][ni][0] + bb.x; v0 = v0 > 0.f ? v0 : 0.f;
            float v1 = acc[mi][ni][1] + bb.y; v1 = v1 > 0.f ? v1 : 0.f;
            float v2 = acc[mi][ni][2] + bb.z; v2 = v2 > 0.f ? v2 : 0.f;
            float v3 = acc[mi][ni][3] + bb.w; v3 = v3 > 0.f ? v3 : 0.f;
            u32x2 d;
            d.x = f2bf(v0) | ((unsigned)f2bf(v1) << 16);
            d.y = f2bf(v2) | ((unsigned)f2bf(v3) << 16);
            int row = ni * 16 + l15;
            int w0c = wl * 64 + mi * 16 + l4 * 4;
            int byte = (row * 256 + w0c) * 2;
            byte ^= (row & 7) << 4;
            *reinterpret_cast<u32x2*>(reinterpret_cast<char*>(h_s) + byte) = d;
        }
    }
}

// GEMM2 (swapped): wave owns out-cols [wl*32, +32) (2 frags), 32 rows (2 frags).
__device__ __forceinline__ void gemm2(
    const unsigned short* h_s, const unsigned short* __restrict__ W2p,
    f32x4 (&acc)[2][2], int l15, int l4, int wl, const bf16x8 (&w01)[2][2])
{
    #pragma unroll
    for (int mi = 0; mi < 2; ++mi)
        #pragma unroll
        for (int ni = 0; ni < 2; ++ni) acc[mi][ni] = (f32x4){0.f, 0.f, 0.f, 0.f};

    const unsigned short* Wbase = W2p + ((l4 * 128 + wl * 32 + l15) << 3);
    bf16x8 wf[3][2], hf[2][2];
    #pragma unroll
    for (int mi = 0; mi < 2; ++mi) {
        wf[0][mi] = w01[0][mi];
        wf[1][mi] = w01[1][mi];
    }
    #pragma unroll
    for (int ni = 0; ni < 2; ++ni) hf[0][ni] = loadA<256>(h_s, 0, ni, l15, l4);

    #pragma unroll
    for (int ks = 0; ks < 8; ++ks) {
        if (ks + 2 < 8) {
            #pragma unroll
            for (int mi = 0; mi < 2; ++mi)
                wf[(ks + 2) % 3][mi] = *reinterpret_cast<const bf16x8*>(
                    Wbase + (ks + 2) * 4096 + (mi << 7));
        }
        if (ks + 1 < 8) {
            #pragma unroll
            for (int ni = 0; ni < 2; ++ni)
                hf[(ks + 1) & 1][ni] = loadA<256>(h_s, ks + 1, ni, l15, l4);
        }
        __builtin_amdgcn_s_setprio(1);
        #pragma unroll
        for (int mi = 0; mi < 2; ++mi)
            #pragma unroll
            for (int ni = 0; ni < 2; ++ni)
                acc[mi][ni] = __builtin_amdgcn_mfma_f32_16x16x32_bf16(
                                  wf[ks % 3][mi], hf[ks & 1][ni], acc[mi][ni], 0, 0, 0);
        __builtin_amdgcn_s_setprio(0);
    }
}

__global__ __launch_bounds__(512, 4)
void fused_sbc(const int* __restrict__ user_ids,  const int* __restrict__ item_ids,
               const float* __restrict__ user_table, const float* __restrict__ item_table,
               const unsigned short* __restrict__ uW1p, const float* __restrict__ ub1,
               const unsigned short* __restrict__ uW2p, const float* __restrict__ ub2,
               const unsigned short* __restrict__ iW1p, const float* __restrict__ ib1,
               const unsigned short* __restrict__ iW2p, const float* __restrict__ ib2,
               const float* __restrict__ sw, float* __restrict__ out,
               int B, int nn1)
{
    __shared__ __align__(16) unsigned short smem[40960];   // 80 KB -> 2 blk/CU
    unsigned short* e_u = smem;                  // [32][512]  32 KB
    unsigned short* e_i = smem + 16384;          // [32][256]  16 KB
    unsigned short* h_u = smem + 24576;          // [32][256]  16 KB
    unsigned short* h_i = smem + 32768;          // [32][256]  16 KB
    float* V_lds = reinterpret_cast<float*>(smem);          // [32][132] over e_u
    float* red   = reinterpret_cast<float*>(smem + 16384);  // [4][32][3] over e_i

    const int tid  = threadIdx.x;
    const int lane = tid & 63;
    const int w    = tid >> 6;
    const int l15  = lane & 15, l4 = lane >> 4;
    const int role = w >> 2;                     // 0 = user, 1 = item
    const int wl   = w & 3;
    const int row0 = blockIdx.x * 32;

    const unsigned short* W1sel = role ? iW1p : uW1p;
    const unsigned short* W2sel = role ? iW2p : uW2p;

    // preload BOTH GEMM1 weight rotation slots (hidden under the HBM gather)
    bf16x8 w1pre[2][4];
    {
        const unsigned short* base = W1sel + ((l4 * 256 + wl * 64 + l15) << 3);
        #pragma unroll
        for (int s = 0; s < 2; ++s)
            #pragma unroll
            for (int mi = 0; mi < 4; ++mi)
                w1pre[s][mi] = *reinterpret_cast<const bf16x8*>(
                                   base + s * 8192 + (mi << 7));
    }
    stage_emb<8>(user_ids, user_table, e_u, row0, tid);
    stage_emb<4>(item_ids, item_table, e_i, row0, tid);
    __syncthreads();                             // B1: embeddings staged

    if (role == 0) gemm1<512>(e_u, h_u, uW1p, ub1, l15, l4, wl, w1pre);
    else           gemm1<256>(e_i, h_i, iW1p, ib1, l15, l4, wl, w1pre);

    // preload BOTH GEMM2 slots (in flight across barrier B2)
    bf16x8 w2pre[2][2];
    {
        const unsigned short* base = W2sel + ((l4 * 128 + wl * 32 + l15) << 3);
        #pragma unroll
        for (int s = 0; s < 2; ++s)
            #pragma unroll
            for (int mi = 0; mi < 2; ++mi)
                w2pre[s][mi] = *reinterpret_cast<const bf16x8*>(
                                   base + s * 4096 + (mi << 7));
    }
    __syncthreads();                             // B2: h_u, h_i ready

    f32x4 acc2[2][2];
    if (role == 0) gemm2(h_u, uW2p, acc2, l15, l4, wl, w2pre);
    else           gemm2(h_i, iW2p, acc2, l15, l4, wl, w2pre);

    // item waves: relu(V) -> V_lds + ||v||^2 partials
    if (role == 1) {
        float pv[2] = {0.f, 0.f};
        #pragma unroll
        for (int mi = 0; mi < 2; ++mi) {
            const int colb = wl * 32 + mi * 16 + l4 * 4;
            const float4 bv = *reinterpret_cast<const float4*>(&ib2[colb]);
            #pragma unroll
            for (int ni = 0; ni < 2; ++ni) {
                int row = ni * 16 + l15;
                float v0 = acc2[mi][ni][0] + bv.x; v0 = v0 > 0.f ? v0 : 0.f;
                float v1 = acc2[mi][ni][1] + bv.y; v1 = v1 > 0.f ? v1 : 0.f;
                float v2 = acc2[mi][ni][2] + bv.z; v2 = v2 > 0.f ? v2 : 0.f;
                float v3 = acc2[mi][ni][3] + bv.w; v3 = v3 > 0.f ? v3 : 0.f;
                float4 vv = {v0, v1, v2, v3};
                *reinterpret_cast<float4*>(&V_lds[row * 132 + colb]) = vv;
                pv[ni] += v0 * v0 + v1 * v1 + v2 * v2 + v3 * v3;
            }
        }
        #pragma unroll
        for (int ni = 0; ni < 2; ++ni) {
            pv[ni] += __shfl_xor(pv[ni], 16);
            pv[ni] += __shfl_xor(pv[ni], 32);
        }
        if (l4 == 0) {
            #pragma unroll
            for (int ni = 0; ni < 2; ++ni)
                red[(wl * 32 + ni * 16 + l15) * 3 + 2] = pv[ni];
        }
    }
    __syncthreads();                             // B3: V published

    // user waves: relu(U), dot + ||u||^2 partials
    if (role == 0) {
        float pd[2] = {0.f, 0.f}, pu[2] = {0.f, 0.f};
        #pragma unroll
        for (int mi = 0; mi < 2; ++mi) {
            const int colb = wl * 32 + mi * 16 + l4 * 4;
            const float4 bu = *reinterpret_cast<const float4*>(&ub2[colb]);
            #pragma unroll
            for (int ni = 0; ni < 2; ++ni) {
                int row = ni * 16 + l15;
                float u0 = acc2[mi][ni][0] + bu.x; u0 = u0 > 0.f ? u0 : 0.f;
                float u1 = acc2[mi][ni][1] + bu.y; u1 = u1 > 0.f ? u1 : 0.f;
                float u2 = acc2[mi][ni][2] + bu.z; u2 = u2 > 0.f ? u2 : 0.f;
                float u3 = acc2[mi][ni][3] + bu.w; u3 = u3 > 0.f ? u3 : 0.f;
                const float4 vv = *reinterpret_cast<const float4*>(
                                      &V_lds[row * 132 + colb]);
                pd[ni] += u0 * vv.x + u1 * vv.y + u2 * vv.z + u3 * vv.w;
                pu[ni] += u0 * u0 + u1 * u1 + u2 * u2 + u3 * u3;
            }
        }
        #pragma unroll
        for (int ni = 0; ni < 2; ++ni) {
            pd[ni] += __shfl_xor(pd[ni], 16);
            pd[ni] += __shfl_xor(pd[ni], 32);
            pu[ni] += __shfl_xor(pu[ni], 16);
            pu[ni] += __shfl_xor(pu[ni], 32);
        }
        if (l4 == 0) {
            #pragma unroll
            for (int ni = 0; ni < 2; ++ni) {
                red[(wl * 32 + ni * 16 + l15) * 3 + 0] = pd[ni];
                red[(wl * 32 + ni * 16 + l15) * 3 + 1] = pu[ni];
            }
        }
    }
    __syncthreads();                             // B4: partials in red

    // final reduce + y + scatter
    if (tid < 32) {
        int row = tid;
        float d = 0.f, su = 0.f, sv = 0.f;
        #pragma unroll
        for (int cg = 0; cg < 4; ++cg) {
            d  += red[(cg * 32 + row) * 3 + 0];
            su += red[(cg * 32 + row) * 3 + 1];
            sv += red[(cg * 32 + row) * 3 + 2];
        }
        float un = fmaxf(sqrtf(su), CEPS);
        float vn = fmaxf(sqrtf(sv), CEPS);
        int grow = row0 + row;
        float yv = d / (un * vn) - logf(sw[grow]);
        for (int j = 0; j < nn1; ++j) {
            int idx = grow - j;
            if (idx < 0) idx += B;
            out[idx * nn1 + j] = yv;
        }
    }
}

extern "C" void kernel_launch(void* const* d_in, const int* in_sizes, int n_in,
                              void* d_out, int out_size, void* d_ws, size_t ws_size,
                              hipStream_t stream)
{
    const int*   user_ids   = (const int*)  d_in[0];
    const int*   item_ids   = (const int*)  d_in[1];
    const float* sw         = (const float*)d_in[2];
    const float* user_table = (const float*)d_in[3];
    const float* item_table = (const float*)d_in[4];
    const float* uW1        = (const float*)d_in[5];
    const float* ub1        = (const float*)d_in[6];
    const float* uW2        = (const float*)d_in[7];
    const float* ub2        = (const float*)d_in[8];
    const float* iW1        = (const float*)d_in[9];
    const float* ib1        = (const float*)d_in[10];
    const float* iW2        = (const float*)d_in[11];
    const float* ib2        = (const float*)d_in[12];

    const int B   = in_sizes[2];       // 16384
    const int nn1 = out_size / B;      // n_neg + 1

    unsigned short* wp   = (unsigned short*)d_ws;
    unsigned short* uW1p = wp;               // 131072
    unsigned short* uW2p = wp + 131072;      // 32768
    unsigned short* iW1p = wp + 163840;      // 65536
    unsigned short* iW2p = wp + 229376;      // 32768
    float* out = (float*)d_out;

    pack_all<<<128, 256, 0, stream>>>(uW1, uW2, iW1, iW2,
                                      uW1p, uW2p, iW1p, iW2p);
    fused_sbc<<<B / 32, 512, 0, stream>>>(user_ids, item_ids,
                                          user_table, item_table,
                                          uW1p, ub1, uW2p, ub2,
                                          iW1p, ib1, iW2p, ib2,
                                          sw, out, B, nn1);
}